// Round 1
// baseline (435.160 us; speedup 1.0000x reference)
//
#include <hip/hip_runtime.h>

// Problem constants: z (16,256,32,32) fp32, emb (4096,256) fp32.
// N = 16*32*32 = 16384 flattened rows, K = 4096 codes, D = 256.
// z_flat[n][d] = z[(n>>10)*262144 + d*1024 + (n&1023)]
#define NN 16384
#define KK 4096
#define DD 256

typedef __attribute__((ext_vector_type(8))) short short8;
typedef __attribute__((ext_vector_type(4))) float f32x4;

static __device__ __forceinline__ unsigned short f2bf(float f) {
  unsigned u = __float_as_uint(f);
  unsigned r = (u + 0x7FFFu + ((u >> 16) & 1u)) >> 16;   // RNE
  return (unsigned short)r;
}

static __device__ __forceinline__ unsigned int mono(float f) {
  unsigned u = __float_as_uint(f);
  return (u & 0x80000000u) ? ~u : (u | 0x80000000u);     // order-preserving map
}

// ---- kernel A: e2[k] = ||emb_k||^2 (fp32 from fp32 source) -----------------
__global__ void vq_e2(const float* __restrict__ emb, float* __restrict__ e2g) {
  int k = blockIdx.x;
  int lane = threadIdx.x;                 // 64 threads = 1 wave
  float4 v = *reinterpret_cast<const float4*>(&emb[k * DD + lane * 4]);
  float s = v.x * v.x + v.y * v.y + v.z * v.z + v.w * v.w;
  #pragma unroll
  for (int o = 1; o < 64; o <<= 1) s += __shfl_xor(s, o);
  if (lane == 0) e2g[k] = s;
}

// ---- kernel B: scores = ||e||^2 - 2*emb@z^T, fused argmin ------------------
// grid.x = 128 n-tiles (128 cols each), grid.y = 4 k-chunks (1024 codes each)
__global__ __launch_bounds__(256) void vq_scores(
    const float* __restrict__ z, const float* __restrict__ emb,
    const float* __restrict__ e2g, unsigned long long* __restrict__ keys) {
  __shared__ unsigned short zt[128][264];   // z tile bf16, [n][d], +8 pad
  __shared__ unsigned short et[64][264];    // emb tile bf16, [k][d]
  __shared__ float e2t[64];

  const int tid = threadIdx.x;
  const int bx = blockIdx.x;
  const int by = blockIdx.y;

  // stage z tile once: rows n0..n0+127 (all inside one batch image)
  const long zbase = (long)(bx >> 3) * 262144 + (long)(bx & 7) * 128;
  {
    int n4 = (tid & 31) << 2;             // 0..124
    int dl = tid >> 5;                    // 0..7
    for (int p = 0; p < 32; ++p) {
      int d = (p << 3) + dl;
      float4 v = *reinterpret_cast<const float4*>(&z[zbase + (long)d * 1024 + n4]);
      zt[n4 + 0][d] = f2bf(v.x);
      zt[n4 + 1][d] = f2bf(v.y);
      zt[n4 + 2][d] = f2bf(v.z);
      zt[n4 + 3][d] = f2bf(v.w);
    }
  }

  const int lane = tid & 63;
  const int wid = tid >> 6;               // 0..3, wave owns 32 n-cols
  const int l16 = lane & 15;
  const int g4 = lane >> 4;               // 0..3

  float bestv0 = INFINITY, bestv1 = INFINITY;
  int besti0 = 0, besti1 = 0;

  for (int kt = 0; kt < 16; ++kt) {
    __syncthreads();                      // protect et from previous readers
    {                                     // stage 64x256 emb tile
      const long ebase = ((long)by * 1024 + (long)kt * 64) * DD;
      for (int p = 0; p < 16; ++p) {
        int idx = (p << 8) + tid;         // 0..4095
        int r = idx >> 6;
        int c4 = (idx & 63) << 2;
        float4 v = *reinterpret_cast<const float4*>(&emb[ebase + r * DD + c4]);
        ushort4 w;
        w.x = f2bf(v.x); w.y = f2bf(v.y); w.z = f2bf(v.z); w.w = f2bf(v.w);
        *reinterpret_cast<ushort4*>(&et[r][c4]) = w;
      }
      if (tid < 64) e2t[tid] = e2g[by * 1024 + kt * 64 + tid];
    }
    __syncthreads();

    f32x4 acc[4][2];
    #pragma unroll
    for (int m = 0; m < 4; ++m)
      #pragma unroll
      for (int r = 0; r < 2; ++r) acc[m][r] = (f32x4){0.f, 0.f, 0.f, 0.f};

    #pragma unroll
    for (int ds = 0; ds < 8; ++ds) {
      const int dcol = ds * 32 + g4 * 8;
      short8 a0 = *reinterpret_cast<const short8*>(&et[ 0 + l16][dcol]);
      short8 a1 = *reinterpret_cast<const short8*>(&et[16 + l16][dcol]);
      short8 a2 = *reinterpret_cast<const short8*>(&et[32 + l16][dcol]);
      short8 a3 = *reinterpret_cast<const short8*>(&et[48 + l16][dcol]);
      short8 b0 = *reinterpret_cast<const short8*>(&zt[wid * 32 + l16][dcol]);
      short8 b1 = *reinterpret_cast<const short8*>(&zt[wid * 32 + 16 + l16][dcol]);
      acc[0][0] = __builtin_amdgcn_mfma_f32_16x16x32_bf16(a0, b0, acc[0][0], 0, 0, 0);
      acc[0][1] = __builtin_amdgcn_mfma_f32_16x16x32_bf16(a0, b1, acc[0][1], 0, 0, 0);
      acc[1][0] = __builtin_amdgcn_mfma_f32_16x16x32_bf16(a1, b0, acc[1][0], 0, 0, 0);
      acc[1][1] = __builtin_amdgcn_mfma_f32_16x16x32_bf16(a1, b1, acc[1][1], 0, 0, 0);
      acc[2][0] = __builtin_amdgcn_mfma_f32_16x16x32_bf16(a2, b0, acc[2][0], 0, 0, 0);
      acc[2][1] = __builtin_amdgcn_mfma_f32_16x16x32_bf16(a2, b1, acc[2][1], 0, 0, 0);
      acc[3][0] = __builtin_amdgcn_mfma_f32_16x16x32_bf16(a3, b0, acc[3][0], 0, 0, 0);
      acc[3][1] = __builtin_amdgcn_mfma_f32_16x16x32_bf16(a3, b1, acc[3][1], 0, 0, 0);
    }

    // epilogue: scores for 64 codes x 32 cols, running first-min per lane
    #pragma unroll
    for (int m = 0; m < 4; ++m) {
      #pragma unroll
      for (int rg = 0; rg < 4; ++rg) {
        int krow = m * 16 + g4 * 4 + rg;       // C row = (lane>>4)*4 + reg
        float e2v = e2t[krow];
        int kk = by * 1024 + kt * 64 + krow;   // ascending scan order per lane
        float s0 = fmaf(-2.0f, acc[m][0][rg], e2v);
        float s1 = fmaf(-2.0f, acc[m][1][rg], e2v);
        if (s0 < bestv0) { bestv0 = s0; besti0 = kk; }
        if (s1 < bestv1) { bestv1 = s1; besti1 = kk; }
      }
    }
  }

  // cross-lane combine (cols live in lanes {l16, +16, +32, +48}) + atomic
  unsigned long long key0 =
      ((unsigned long long)mono(bestv0) << 32) | (unsigned)besti0;
  unsigned long long key1 =
      ((unsigned long long)mono(bestv1) << 32) | (unsigned)besti1;
  unsigned long long o;
  o = __shfl_xor(key0, 16); if (o < key0) key0 = o;
  o = __shfl_xor(key0, 32); if (o < key0) key0 = o;
  o = __shfl_xor(key1, 16); if (o < key1) key1 = o;
  o = __shfl_xor(key1, 32); if (o < key1) key1 = o;
  if (g4 == 0) {
    int n0 = bx * 128 + wid * 32 + l16;
    atomicMin(&keys[n0], key0);
    atomicMin(&keys[n0 + 16], key1);
  }
}

// ---- kernel C: gather quantized, loss partials, one-hot, counts ------------
__global__ __launch_bounds__(256) void vq_finish(
    const float* __restrict__ z, const float* __restrict__ emb,
    const unsigned long long* __restrict__ keys, unsigned int* __restrict__ counts,
    float* __restrict__ lossacc, float* __restrict__ outq, float* __restrict__ enc) {
  __shared__ float ztile[64][257];
  __shared__ int sidx[64];
  __shared__ float wsum[4];

  const int tid = threadIdx.x;
  const int n0 = blockIdx.x * 64;
  const long zbase = (long)(n0 >> 10) * 262144 + (long)(n0 & 1023);

  {
    int n4 = (tid & 15) << 2;            // 0..60
    int dl = tid >> 4;                   // 0..15
    for (int p = 0; p < 16; ++p) {
      int d = p * 16 + dl;
      float4 v = *reinterpret_cast<const float4*>(&z[zbase + (long)d * 1024 + n4]);
      ztile[n4 + 0][d] = v.x;
      ztile[n4 + 1][d] = v.y;
      ztile[n4 + 2][d] = v.z;
      ztile[n4 + 3][d] = v.w;
    }
  }
  if (tid < 64) {
    int n = n0 + tid;
    int idx = (int)(keys[n] & 0xFFFFFFFFULL);
    sidx[tid] = idx;
    atomicAdd(&counts[idx], 1u);
    enc[(long)n * KK + idx] = 1.0f;      // rest of row zeroed by memset
  }
  __syncthreads();

  float lacc = 0.f;
  const int d = tid;                     // 256 threads == D
  for (int nl = 0; nl < 64; ++nl) {
    int idx = sidx[nl];
    float e = emb[idx * DD + d];         // coalesced row read
    float zz = ztile[nl][d];
    float df = e - zz;
    lacc += df * df;
    outq[(long)(n0 + nl) * DD + d] = zz + (e - zz);  // replicate fp32 STE rounding
  }
  #pragma unroll
  for (int o = 1; o < 64; o <<= 1) lacc += __shfl_xor(lacc, o);
  if ((tid & 63) == 0) wsum[tid >> 6] = lacc;
  __syncthreads();
  if (tid == 0) atomicAdd(lossacc, wsum[0] + wsum[1] + wsum[2] + wsum[3]);
}

// ---- kernel D: scalars ------------------------------------------------------
__global__ void vq_scalars(const unsigned int* __restrict__ counts,
                           const float* __restrict__ lossacc,
                           float* __restrict__ outs) {
  __shared__ double sh[256];
  int t = threadIdx.x;
  double ent = 0.0;
  for (int k = t; k < KK; k += 256) {
    double p = (double)counts[k] / (double)NN;
    ent += p * log(p + 1e-10);
  }
  sh[t] = ent;
  __syncthreads();
  for (int s = 128; s > 0; s >>= 1) {
    if (t < s) sh[t] += sh[t + s];
    __syncthreads();
  }
  if (t == 0) {
    outs[0] = lossacc[0] * 1.25f / ((float)NN * (float)DD);  // q_loss + 0.25*e_loss
    outs[1] = (float)exp(-sh[0]);                            // perplexity
  }
}

extern "C" void kernel_launch(void* const* d_in, const int* in_sizes, int n_in,
                              void* d_out, int out_size, void* d_ws, size_t ws_size,
                              hipStream_t stream) {
  const float* z = (const float*)d_in[0];
  const float* emb = (const float*)d_in[1];
  float* out = (float*)d_out;
  float* outq = out;                       // 4194304 elements (B,D,H,W flat)
  float* outs = out + 4194304;             // loss, perplexity
  float* enc = out + 4194306;              // 16384*4096 one-hot

  char* ws = (char*)d_ws;
  unsigned long long* keys = (unsigned long long*)ws;        // 131072 B
  unsigned int* counts = (unsigned int*)(ws + 131072);       // 16384 B
  float* lossacc = (float*)(ws + 147456);                    // 4 B
  float* e2g = (float*)(ws + 147472);                        // 16384 B

  hipMemsetAsync(keys, 0xFF, 131072, stream);                // +inf keys
  hipMemsetAsync(ws + 131072, 0, 16388, stream);             // counts + lossacc
  hipMemsetAsync(enc, 0, (size_t)NN * KK * 4, stream);       // 268 MB one-hot zero

  vq_e2<<<KK, 64, 0, stream>>>(emb, e2g);
  vq_scores<<<dim3(NN / 128, 4), 256, 0, stream>>>(z, emb, e2g, keys);
  vq_finish<<<NN / 64, 256, 0, stream>>>(z, emb, keys, counts, lossacc, outq, enc);
  vq_scalars<<<1, 256, 0, stream>>>(counts, lossacc, outs);
}

// Round 2
// 396.404 us; speedup vs baseline: 1.0978x; 1.0978x over previous
//
#include <hip/hip_runtime.h>

// z (16,256,32,32) fp32, emb (4096,256) fp32.
// N = 16384 rows, K = 4096 codes, D = 256 (GEMM reduction dim).
// z_flat[n][d] = z[(n>>10)*262144 + d*1024 + (n&1023)]
#define NN 16384
#define KK 4096
#define DD 256

typedef __attribute__((ext_vector_type(8))) short short8;
typedef __attribute__((ext_vector_type(4))) float f32x4;

static __device__ __forceinline__ unsigned short f2bf(float f) {
  unsigned u = __float_as_uint(f);
  return (unsigned short)((u + 0x7FFFu + ((u >> 16) & 1u)) >> 16);  // RNE
}

static __device__ __forceinline__ unsigned int mono(float f) {
  unsigned u = __float_as_uint(f);
  return (u & 0x80000000u) ? ~u : (u | 0x80000000u);  // order-preserving
}

// ---- P1: emb fp32 -> bf16, plus e2[k] = ||emb_k||^2 (fp32) ----------------
__global__ __launch_bounds__(256) void vq_prep_emb(
    const float* __restrict__ emb, unsigned short* __restrict__ eb,
    float* __restrict__ e2g) {
  const int wid = threadIdx.x >> 6, lane = threadIdx.x & 63;
  const int row = blockIdx.x * 4 + wid;
  float4 v = *reinterpret_cast<const float4*>(&emb[row * DD + lane * 4]);
  ushort4 w;
  w.x = f2bf(v.x); w.y = f2bf(v.y); w.z = f2bf(v.z); w.w = f2bf(v.w);
  *reinterpret_cast<ushort4*>(&eb[row * DD + lane * 4]) = w;
  float s = v.x * v.x + v.y * v.y + v.z * v.z + v.w * v.w;
  #pragma unroll
  for (int o = 1; o < 64; o <<= 1) s += __shfl_xor(s, o);
  if (lane == 0) e2g[row] = s;
}

// ---- P2: z (B,D,H,W) fp32 -> zb[n][d] bf16 (transpose via LDS) ------------
__global__ __launch_bounds__(256) void vq_prep_z(
    const float* __restrict__ z, unsigned short* __restrict__ zb) {
  __shared__ unsigned short t[64][72];   // 72*2=144 B row stride, 16B-aligned
  const int tid = threadIdx.x;
  const int bx = blockIdx.x;
  const int b = bx >> 6, rem = bx & 63, dt = rem >> 4, ht = rem & 15;
  const float* src = z + (long)b * 262144 + (long)dt * 64 * 1024 + ht * 64;
  #pragma unroll
  for (int p = 0; p < 16; ++p) {
    int idx = p * 256 + tid;
    int dl = idx >> 6, hl = idx & 63;    // consecutive lanes -> consecutive hw
    t[hl][dl] = f2bf(src[dl * 1024 + hl]);
  }
  __syncthreads();
  unsigned short* dst = zb + ((long)b * 1024 + (long)ht * 64) * DD + dt * 64;
  #pragma unroll
  for (int p = 0; p < 2; ++p) {
    int idx = p * 256 + tid;
    int hl = idx >> 3, c8 = idx & 7;
    short8 v = *reinterpret_cast<const short8*>(&t[hl][c8 * 8]);
    *reinterpret_cast<short8*>(&dst[(long)hl * DD + c8 * 8]) = v;
  }
}

// ---- G: scores = ||e||^2 - 2*eb@zb^T, fused argmin (m97 structure) --------
// grid (32 M-blocks of 128 codes, 128 N-blocks of 128 cols), 256 threads
__global__ __launch_bounds__(256) void vq_gemm(
    const unsigned short* __restrict__ eb, const unsigned short* __restrict__ zb,
    const float* __restrict__ e2g, unsigned long long* __restrict__ keys) {
  __shared__ unsigned short At[128 * 64];   // [row][64] linear (global_load_lds)
  __shared__ unsigned short Bt[128 * 64];
  __shared__ float e2s[128];
  __shared__ unsigned long long wkey[2][128];

  const int tid = threadIdx.x;
  const int bm = blockIdx.x;               // code tile
  const int bn = blockIdx.y;               // n tile
  const int lane = tid & 63, wid = tid >> 6;
  const int wm = wid >> 1, wn = wid & 1;   // wave -> 64x64 sub-tile
  const int l16 = lane & 15, g4 = lane >> 4;

  if (tid < 128) {
    e2s[tid] = e2g[bm * 128 + tid];
    wkey[0][tid] = ~0ull;
    wkey[1][tid] = ~0ull;
  }

  const long abase = (long)bm * 128 * DD;
  const long bbase = (long)bn * 128 * DD;

  f32x4 acc[4][4];
  #pragma unroll
  for (int mi = 0; mi < 4; ++mi)
    #pragma unroll
    for (int ni = 0; ni < 4; ++ni) acc[mi][ni] = (f32x4){0.f, 0.f, 0.f, 0.f};

  for (int kt = 0; kt < 4; ++kt) {
    __syncthreads();                       // readers of At/Bt done
    {                                      // stage 128x64 A and B tiles
      const int lr = lane >> 3, lc = (lane & 7) * 8;   // row-in-8, col elems
      #pragma unroll
      for (int c = 0; c < 4; ++c) {
        const int row0 = wid * 32 + c * 8;
        const unsigned short* ga =
            eb + abase + (long)(row0 + lr) * DD + kt * 64 + lc;
        __builtin_amdgcn_global_load_lds(
            (const __attribute__((address_space(1))) void*)ga,
            (__attribute__((address_space(3))) void*)&At[row0 * 64], 16, 0, 0);
        const unsigned short* gb =
            zb + bbase + (long)(row0 + lr) * DD + kt * 64 + lc;
        __builtin_amdgcn_global_load_lds(
            (const __attribute__((address_space(1))) void*)gb,
            (__attribute__((address_space(3))) void*)&Bt[row0 * 64], 16, 0, 0);
      }
    }
    __syncthreads();                       // vmcnt(0) drained by compiler

    #pragma unroll
    for (int kk = 0; kk < 2; ++kk) {
      short8 a[4], b[4];
      #pragma unroll
      for (int mi = 0; mi < 4; ++mi)
        a[mi] = *reinterpret_cast<const short8*>(
            &At[(wm * 64 + mi * 16 + l16) * 64 + kk * 32 + g4 * 8]);
      #pragma unroll
      for (int ni = 0; ni < 4; ++ni)
        b[ni] = *reinterpret_cast<const short8*>(
            &Bt[(wn * 64 + ni * 16 + l16) * 64 + kk * 32 + g4 * 8]);
      #pragma unroll
      for (int mi = 0; mi < 4; ++mi)
        #pragma unroll
        for (int ni = 0; ni < 4; ++ni)
          acc[mi][ni] = __builtin_amdgcn_mfma_f32_16x16x32_bf16(
              a[mi], b[ni], acc[mi][ni], 0, 0, 0);
    }
  }

  // epilogue: per-column running first-min over this block's 128 codes
  #pragma unroll
  for (int ni = 0; ni < 4; ++ni) {
    float bv = INFINITY;
    int bi = 0;
    #pragma unroll
    for (int mi = 0; mi < 4; ++mi) {
      #pragma unroll
      for (int r = 0; r < 4; ++r) {
        int krow = wm * 64 + mi * 16 + g4 * 4 + r;   // C row = (lane>>4)*4+reg
        float s = fmaf(-2.0f, acc[mi][ni][r], e2s[krow]);
        if (s < bv) { bv = s; bi = bm * 128 + krow; }
      }
    }
    unsigned long long key =
        ((unsigned long long)mono(bv) << 32) | (unsigned)bi;
    unsigned long long o;
    o = __shfl_xor(key, 16); if (o < key) key = o;
    o = __shfl_xor(key, 32); if (o < key) key = o;
    if (g4 == 0) wkey[wm][wn * 64 + ni * 16 + l16] = key;  // no collision
  }
  __syncthreads();
  if (tid < 128) {
    unsigned long long k0 = wkey[0][tid], k1 = wkey[1][tid];
    atomicMin(&keys[(long)bn * 128 + tid], k0 < k1 ? k0 : k1);
  }
}

// ---- C: gather quantized, loss partials, one-hot, counts ------------------
__global__ __launch_bounds__(256) void vq_finish(
    const float* __restrict__ z, const float* __restrict__ emb,
    const unsigned long long* __restrict__ keys, unsigned int* __restrict__ counts,
    float* __restrict__ lossacc, float* __restrict__ outq, float* __restrict__ enc) {
  __shared__ float ztile[64][257];
  __shared__ int sidx[64];
  __shared__ float wsum[4];

  const int tid = threadIdx.x;
  const int n0 = blockIdx.x * 64;
  const long zbase = (long)(n0 >> 10) * 262144 + (long)(n0 & 1023);

  {
    int n4 = (tid & 15) << 2;
    int dl = tid >> 4;
    for (int p = 0; p < 16; ++p) {
      int d = p * 16 + dl;
      float4 v = *reinterpret_cast<const float4*>(&z[zbase + (long)d * 1024 + n4]);
      ztile[n4 + 0][d] = v.x;
      ztile[n4 + 1][d] = v.y;
      ztile[n4 + 2][d] = v.z;
      ztile[n4 + 3][d] = v.w;
    }
  }
  if (tid < 64) {
    int n = n0 + tid;
    int idx = (int)(keys[n] & 0xFFFFFFFFULL);
    sidx[tid] = idx;
    atomicAdd(&counts[idx], 1u);
    enc[(long)n * KK + idx] = 1.0f;        // rest of row zeroed by memset
  }
  __syncthreads();

  float lacc = 0.f;
  const int d = tid;                       // 256 threads == D
  for (int nl = 0; nl < 64; ++nl) {
    int idx = sidx[nl];
    float e = emb[idx * DD + d];
    float zz = ztile[nl][d];
    float df = e - zz;
    lacc += df * df;
    outq[(long)(n0 + nl) * DD + d] = zz + (e - zz);   // fp32 STE rounding
  }
  #pragma unroll
  for (int o = 1; o < 64; o <<= 1) lacc += __shfl_xor(lacc, o);
  if ((tid & 63) == 0) wsum[tid >> 6] = lacc;
  __syncthreads();
  if (tid == 0) atomicAdd(lossacc, wsum[0] + wsum[1] + wsum[2] + wsum[3]);
}

// ---- D: scalars ------------------------------------------------------------
__global__ void vq_scalars(const unsigned int* __restrict__ counts,
                           const float* __restrict__ lossacc,
                           float* __restrict__ outs) {
  __shared__ double sh[256];
  int t = threadIdx.x;
  double ent = 0.0;
  for (int k = t; k < KK; k += 256) {
    double p = (double)counts[k] / (double)NN;
    ent += p * log(p + 1e-10);
  }
  sh[t] = ent;
  __syncthreads();
  for (int s = 128; s > 0; s >>= 1) {
    if (t < s) sh[t] += sh[t + s];
    __syncthreads();
  }
  if (t == 0) {
    outs[0] = lossacc[0] * 1.25f / ((float)NN * (float)DD);
    outs[1] = (float)exp(-sh[0]);
  }
}

extern "C" void kernel_launch(void* const* d_in, const int* in_sizes, int n_in,
                              void* d_out, int out_size, void* d_ws, size_t ws_size,
                              hipStream_t stream) {
  const float* z = (const float*)d_in[0];
  const float* emb = (const float*)d_in[1];
  float* out = (float*)d_out;
  float* outq = out;                        // 4194304 elems
  float* outs = out + 4194304;              // loss, perplexity
  float* enc = out + 4194306;               // 16384*4096 one-hot

  char* ws = (char*)d_ws;
  unsigned short* zb = (unsigned short*)ws;                   // 8 MB
  unsigned short* eb = (unsigned short*)(ws + 8388608);       // 2 MB
  float* e2g = (float*)(ws + 10485760);                       // 16 KB
  unsigned long long* keys = (unsigned long long*)(ws + 10502144);  // 128 KB
  unsigned int* counts = (unsigned int*)(ws + 10633216);      // 16 KB
  float* lossacc = (float*)(ws + 10649600);                   // 4 B

  hipMemsetAsync(keys, 0xFF, 131072, stream);
  hipMemsetAsync(ws + 10633216, 0, 16388, stream);            // counts+lossacc
  hipMemsetAsync(enc, 0, (size_t)NN * KK * 4, stream);        // 268 MB

  vq_prep_emb<<<1024, 256, 0, stream>>>(emb, eb, e2g);
  vq_prep_z<<<1024, 256, 0, stream>>>(z, zb);
  vq_gemm<<<dim3(32, 128), 256, 0, stream>>>(eb, zb, e2g, keys);
  vq_finish<<<NN / 64, 256, 0, stream>>>(z, emb, keys, counts, lossacc, outq, enc);
  vq_scalars<<<1, 256, 0, stream>>>(counts, lossacc, outs);
}

// Round 3
// 352.542 us; speedup vs baseline: 1.2343x; 1.1244x over previous
//
#include <hip/hip_runtime.h>

// z (16,256,32,32) fp32, emb (4096,256) fp32.
// N = 16384 rows, K = 4096 codes, D = 256 (GEMM reduction dim).
// z_flat[n][d] = z[(n>>10)*262144 + d*1024 + (n&1023)]
#define NN 16384
#define KK 4096
#define DD 256

typedef __attribute__((ext_vector_type(8))) short short8;
typedef __attribute__((ext_vector_type(4))) float f32x4;

static __device__ __forceinline__ unsigned short f2bf(float f) {
  unsigned u = __float_as_uint(f);
  return (unsigned short)((u + 0x7FFFu + ((u >> 16) & 1u)) >> 16);  // RNE
}

static __device__ __forceinline__ unsigned int mono(float f) {
  unsigned u = __float_as_uint(f);
  return (u & 0x80000000u) ? ~u : (u | 0x80000000u);  // order-preserving
}

// ---- P: fused prep. blocks 0..1023: z->bf16 transpose; 1024..2047: emb->bf16
//         + ||e||^2; 2048..2055: keys/counts/lossacc init. ------------------
__global__ __launch_bounds__(256) void vq_prep(
    const float* __restrict__ z, const float* __restrict__ emb,
    unsigned short* __restrict__ zb, unsigned short* __restrict__ eb,
    float* __restrict__ e2g, unsigned long long* __restrict__ keys,
    unsigned int* __restrict__ counts, float* __restrict__ lossacc) {
  __shared__ unsigned short t[64][72];
  const int tid = threadIdx.x;
  const int bx = blockIdx.x;

  if (bx < 1024) {                       // z transpose tile
    const int b = bx >> 6, rem = bx & 63, dt = rem >> 4, ht = rem & 15;
    const float* src = z + (long)b * 262144 + (long)dt * 65536 + ht * 64;
    #pragma unroll
    for (int p = 0; p < 16; ++p) {
      int idx = p * 256 + tid;
      int dl = idx >> 6, hl = idx & 63;  // consecutive lanes -> consecutive hw
      t[hl][dl] = f2bf(src[dl * 1024 + hl]);
    }
    __syncthreads();
    unsigned short* dst = zb + ((long)b * 1024 + (long)ht * 64) * DD + dt * 64;
    #pragma unroll
    for (int p = 0; p < 2; ++p) {
      int idx = p * 256 + tid;
      int hl = idx >> 3, c8 = idx & 7;
      short8 v = *reinterpret_cast<const short8*>(&t[hl][c8 * 8]);
      *reinterpret_cast<short8*>(&dst[(long)hl * DD + c8 * 8]) = v;
    }
  } else if (bx < 2048) {                // emb convert + norms
    const int wid = tid >> 6, lane = tid & 63;
    const int row = (bx - 1024) * 4 + wid;
    float4 v = *reinterpret_cast<const float4*>(&emb[row * DD + lane * 4]);
    ushort4 w;
    w.x = f2bf(v.x); w.y = f2bf(v.y); w.z = f2bf(v.z); w.w = f2bf(v.w);
    *reinterpret_cast<ushort4*>(&eb[row * DD + lane * 4]) = w;
    float s = v.x * v.x + v.y * v.y + v.z * v.z + v.w * v.w;
    #pragma unroll
    for (int o = 1; o < 64; o <<= 1) s += __shfl_xor(s, o);
    if (lane == 0) e2g[row] = s;
  } else {                               // init keys (+inf), counts, lossacc
    int tt = (bx - 2048) * 256 + tid;    // 0..2047
    #pragma unroll
    for (int i = 0; i < 8; ++i) keys[tt * 8 + i] = ~0ull;
    counts[tt * 2] = 0u;
    counts[tt * 2 + 1] = 0u;
    if (tt == 0) lossacc[0] = 0.f;
  }
}

// ---- G: scores = ||e||^2 - 2*eb@zb^T, fused argmin + enc zero-fill --------
// grid (32 M-blocks of 128 codes, 128 N-blocks of 128 cols), 256 threads
__global__ __launch_bounds__(256) void vq_gemm(
    const unsigned short* __restrict__ eb, const unsigned short* __restrict__ zb,
    const float* __restrict__ e2g, unsigned long long* __restrict__ keys,
    float* __restrict__ enc) {
  __shared__ unsigned short At[128 * 64];   // [row][64] linear (global_load_lds)
  __shared__ unsigned short Bt[128 * 64];
  __shared__ float e2s[128];
  __shared__ unsigned long long wkey[2][128];

  const int tid = threadIdx.x;
  const int bm = blockIdx.x;               // code tile
  const int bn = blockIdx.y;               // n tile
  const int lane = tid & 63, wid = tid >> 6;
  const int wm = wid >> 1, wn = wid & 1;   // wave -> 64x64 sub-tile
  const int l16 = lane & 15, g4 = lane >> 4;

  if (tid < 128) {
    e2s[tid] = e2g[bm * 128 + tid];
    wkey[0][tid] = ~0ull;
    wkey[1][tid] = ~0ull;
  }

  const long abase = (long)bm * 128 * DD;
  const long bbase = (long)bn * 128 * DD;

  f32x4 acc[4][4];
  #pragma unroll
  for (int mi = 0; mi < 4; ++mi)
    #pragma unroll
    for (int ni = 0; ni < 4; ++ni) acc[mi][ni] = (f32x4){0.f, 0.f, 0.f, 0.f};

  for (int kt = 0; kt < 4; ++kt) {
    __syncthreads();                       // readers of At/Bt done
    {                                      // stage 128x64 A and B tiles
      const int lr = lane >> 3, lc = (lane & 7) * 8;
      #pragma unroll
      for (int c = 0; c < 4; ++c) {
        const int row0 = wid * 32 + c * 8;
        const unsigned short* ga =
            eb + abase + (long)(row0 + lr) * DD + kt * 64 + lc;
        __builtin_amdgcn_global_load_lds(
            (const __attribute__((address_space(1))) void*)ga,
            (__attribute__((address_space(3))) void*)&At[row0 * 64], 16, 0, 0);
        const unsigned short* gb =
            zb + bbase + (long)(row0 + lr) * DD + kt * 64 + lc;
        __builtin_amdgcn_global_load_lds(
            (const __attribute__((address_space(1))) void*)gb,
            (__attribute__((address_space(3))) void*)&Bt[row0 * 64], 16, 0, 0);
      }
    }
    __syncthreads();                       // vmcnt(0) drained by compiler

    #pragma unroll
    for (int kk = 0; kk < 2; ++kk) {
      short8 a[4], b[4];
      #pragma unroll
      for (int mi = 0; mi < 4; ++mi)
        a[mi] = *reinterpret_cast<const short8*>(
            &At[(wm * 64 + mi * 16 + l16) * 64 + kk * 32 + g4 * 8]);
      #pragma unroll
      for (int ni = 0; ni < 4; ++ni)
        b[ni] = *reinterpret_cast<const short8*>(
            &Bt[(wn * 64 + ni * 16 + l16) * 64 + kk * 32 + g4 * 8]);
      #pragma unroll
      for (int mi = 0; mi < 4; ++mi)
        #pragma unroll
        for (int ni = 0; ni < 4; ++ni)
          acc[mi][ni] = __builtin_amdgcn_mfma_f32_16x16x32_bf16(
              a[mi], b[ni], acc[mi][ni], 0, 0, 0);
    }
  }

  // epilogue: per-column running first-min over this block's 128 codes
  #pragma unroll
  for (int ni = 0; ni < 4; ++ni) {
    float bv = INFINITY;
    int bi = 0;
    #pragma unroll
    for (int mi = 0; mi < 4; ++mi) {
      #pragma unroll
      for (int r = 0; r < 4; ++r) {
        int krow = wm * 64 + mi * 16 + g4 * 4 + r;   // C row = (lane>>4)*4+reg
        float s = fmaf(-2.0f, acc[mi][ni][r], e2s[krow]);
        if (s < bv) { bv = s; bi = bm * 128 + krow; }
      }
    }
    unsigned long long key =
        ((unsigned long long)mono(bv) << 32) | (unsigned)bi;
    unsigned long long o;
    o = __shfl_xor(key, 16); if (o < key) key = o;
    o = __shfl_xor(key, 32); if (o < key) key = o;
    if (g4 == 0) wkey[wm][wn * 64 + ni * 16 + l16] = key;
  }
  __syncthreads();
  if (tid < 128) {
    unsigned long long k0 = wkey[0][tid], k1 = wkey[1][tid];
    atomicMin(&keys[(long)bn * 128 + tid], k0 < k1 ? k0 : k1);
  }

  // enc zero-fill: this block's private 64 KB slice; stores issued after the
  // last barrier so no vmcnt(0) drain waits on them -> overlap with compute
  // of other resident blocks. 16 iters x 256 thr x 16 B = 65536 B.
  {
    const long base = ((long)(bm * 128 + bn)) * 16384;  // floats
    const f32x4 zero4 = (f32x4){0.f, 0.f, 0.f, 0.f};
    #pragma unroll
    for (int i = 0; i < 16; ++i)
      *reinterpret_cast<f32x4*>(&enc[base + (long)(i * 256 + tid) * 4]) = zero4;
  }
}

// ---- C: gather quantized, loss partials, one-hot, counts ------------------
__global__ __launch_bounds__(256) void vq_finish(
    const float* __restrict__ z, const float* __restrict__ emb,
    const unsigned long long* __restrict__ keys, unsigned int* __restrict__ counts,
    float* __restrict__ lossacc, float* __restrict__ outq, float* __restrict__ enc) {
  __shared__ float ztile[64][257];
  __shared__ int sidx[64];
  __shared__ float wsum[4];

  const int tid = threadIdx.x;
  const int n0 = blockIdx.x * 64;
  const long zbase = (long)(n0 >> 10) * 262144 + (long)(n0 & 1023);

  {
    int n4 = (tid & 15) << 2;
    int dl = tid >> 4;
    for (int p = 0; p < 16; ++p) {
      int d = p * 16 + dl;
      float4 v = *reinterpret_cast<const float4*>(&z[zbase + (long)d * 1024 + n4]);
      ztile[n4 + 0][d] = v.x;
      ztile[n4 + 1][d] = v.y;
      ztile[n4 + 2][d] = v.z;
      ztile[n4 + 3][d] = v.w;
    }
  }
  if (tid < 64) {
    int n = n0 + tid;
    int idx = (int)(keys[n] & 0xFFFFFFFFULL);
    sidx[tid] = idx;
    atomicAdd(&counts[idx], 1u);
    enc[(long)n * KK + idx] = 1.0f;        // rest of row zeroed by vq_gemm
  }
  __syncthreads();

  float lacc = 0.f;
  const int d = tid;                       // 256 threads == D
  for (int nl = 0; nl < 64; ++nl) {
    int idx = sidx[nl];
    float e = emb[idx * DD + d];
    float zz = ztile[nl][d];
    float df = e - zz;
    lacc += df * df;
    outq[(long)(n0 + nl) * DD + d] = zz + (e - zz);   // fp32 STE rounding
  }
  #pragma unroll
  for (int o = 1; o < 64; o <<= 1) lacc += __shfl_xor(lacc, o);
  if ((tid & 63) == 0) wsum[tid >> 6] = lacc;
  __syncthreads();
  if (tid == 0) atomicAdd(lossacc, wsum[0] + wsum[1] + wsum[2] + wsum[3]);
}

// ---- D: scalars ------------------------------------------------------------
__global__ void vq_scalars(const unsigned int* __restrict__ counts,
                           const float* __restrict__ lossacc,
                           float* __restrict__ outs) {
  __shared__ double sh[256];
  int t = threadIdx.x;
  double ent = 0.0;
  for (int k = t; k < KK; k += 256) {
    double p = (double)counts[k] / (double)NN;
    ent += p * log(p + 1e-10);
  }
  sh[t] = ent;
  __syncthreads();
  for (int s = 128; s > 0; s >>= 1) {
    if (t < s) sh[t] += sh[t + s];
    __syncthreads();
  }
  if (t == 0) {
    outs[0] = lossacc[0] * 1.25f / ((float)NN * (float)DD);
    outs[1] = (float)exp(-sh[0]);
  }
}

extern "C" void kernel_launch(void* const* d_in, const int* in_sizes, int n_in,
                              void* d_out, int out_size, void* d_ws, size_t ws_size,
                              hipStream_t stream) {
  const float* z = (const float*)d_in[0];
  const float* emb = (const float*)d_in[1];
  float* out = (float*)d_out;
  float* outq = out;                        // 4194304 elems
  float* outs = out + 4194304;              // loss, perplexity
  float* enc = out + 4194306;               // 16384*4096 one-hot

  char* ws = (char*)d_ws;
  unsigned short* zb = (unsigned short*)ws;                   // 8 MB
  unsigned short* eb = (unsigned short*)(ws + 8388608);       // 2 MB
  float* e2g = (float*)(ws + 10485760);                       // 16 KB
  unsigned long long* keys = (unsigned long long*)(ws + 10502144);  // 128 KB
  unsigned int* counts = (unsigned int*)(ws + 10633216);      // 16 KB
  float* lossacc = (float*)(ws + 10649600);                   // 4 B

  vq_prep<<<2056, 256, 0, stream>>>(z, emb, zb, eb, e2g, keys, counts, lossacc);
  vq_gemm<<<dim3(32, 128), 256, 0, stream>>>(eb, zb, e2g, keys, enc);
  vq_finish<<<NN / 64, 256, 0, stream>>>(z, emb, keys, counts, lossacc, outq, enc);
  vq_scalars<<<1, 256, 0, stream>>>(counts, lossacc, outs);
}